// Round 5
// baseline (8789.914 us; speedup 1.0000x reference)
//
#include <hip/hip_runtime.h>
#include <hip/hip_bf16.h>

// LSTM: B=1024, T=512, I=64, H=256, O=1
// Round 4: fully register-resident W_hh in ONE 1024-thread WG per 16 batch
// rows. grid = 64 WGs x 1024 thr (16 waves, 4/SIMD, 1 WG/CU).
//  Wave w owns hidden cols [16w,16w+16): all 4 gates for those cols ->
//  nonlinearity + c update wave-local. Per lane: W_hh slice 4 gates x 8
//  kfrags = 128 VGPR bf16, W_ih 32 VGPR. h exchanged via double-buffered
//  XOR-swizzled bf16 LDS, ONE __syncthreads per step. No cross-WG traffic,
//  no workspace, no atomics. x(t+1) projection MFMAs issued before step-t
//  nonlinearity to overlap matrix pipe with VALU/trans pipes.

typedef float f32x4 __attribute__((ext_vector_type(4)));
typedef short s16x8 __attribute__((ext_vector_type(8)));

#define TT 512
#define II 64
#define HH 256

__device__ __forceinline__ ushort f2bf(float f) {
  unsigned u = __builtin_bit_cast(unsigned, f);
  u = (u + 0x7FFFu + ((u >> 16) & 1u)) >> 16;  // RNE
  return (ushort)u;
}

__device__ __forceinline__ float sigm(float x) {
  return 1.0f / (1.0f + __expf(-x));
}
// overflow-safe tanh
__device__ __forceinline__ float tanh_s(float x) {
  float e = __expf(-2.0f * fabsf(x));
  float t = (1.0f - e) / (1.0f + e);
  return copysignf(t, x);
}

__device__ __forceinline__ s16x8 pack_bf8(const float* p) {
  f32x4 a = *(const f32x4*)p;
  f32x4 b = *(const f32x4*)(p + 4);
  s16x8 r;
  r[0] = (short)f2bf(a[0]); r[1] = (short)f2bf(a[1]);
  r[2] = (short)f2bf(a[2]); r[3] = (short)f2bf(a[3]);
  r[4] = (short)f2bf(b[0]); r[5] = (short)f2bf(b[1]);
  r[6] = (short)f2bf(b[2]); r[7] = (short)f2bf(b[3]);
  return r;
}

__global__ __launch_bounds__(1024, 4) void lstm_one(
    const float* __restrict__ x,      // [B,T,I]
    const float* __restrict__ wih_f,  // [4H,I]
    const float* __restrict__ whh_f,  // [4H,H]
    const float* __restrict__ b_ih,   // [4H]
    const float* __restrict__ b_hh,   // [4H]
    const float* __restrict__ w_out,  // [1,H]
    const float* __restrict__ b_out,  // [1]
    float* __restrict__ out)          // [B]
{
  __shared__ ushort h_lds[2][16 * 256];  // bf16 h, XOR-swizzled, double-buffered
  __shared__ float hf[16][256];          // final-step fp32 h

  const int tid  = threadIdx.x;
  const int wv   = tid >> 6;         // 0..15
  const int l    = tid & 63;
  const int lrow = l & 15;           // A row / B col within 16x16 tile
  const int lk8  = (l >> 4) << 3;    // k offset base for A/B frags
  const int crow = (l >> 4) << 2;    // C row base (+reg idx)
  const int ccol = l & 15;           // C col
  const int b0   = blockIdx.x << 4;  // batch base
  const int col0 = wv << 4;          // hidden col base for this wave

  // ---- load weights into registers (fp32 -> bf16 once) ----
  s16x8 whh[4][8];  // [gate][kfrag]
  s16x8 wih[4][2];
  float bs[4];
#pragma unroll
  for (int g = 0; g < 4; ++g) {
    const int wrow = g * 256 + col0 + lrow;
#pragma unroll
    for (int kf = 0; kf < 8; ++kf)
      whh[g][kf] = pack_bf8(whh_f + wrow * HH + kf * 32 + lk8);
#pragma unroll
    for (int kf = 0; kf < 2; ++kf)
      wih[g][kf] = pack_bf8(wih_f + wrow * II + kf * 32 + lk8);
    const int c = g * 256 + col0 + ccol;
    bs[g] = b_ih[c] + b_hh[c];
  }

  float cst[4] = {0.f, 0.f, 0.f, 0.f};

  // accn = bias + x(0) @ W_ih^T  (x-projection for the upcoming step)
  f32x4 accn[4];
  {
    const float* xp = x + (size_t)(b0 + lrow) * TT * II + lk8;
    s16x8 x0 = pack_bf8(xp);
    s16x8 x1 = pack_bf8(xp + 32);
#pragma unroll
    for (int g = 0; g < 4; ++g) {
      f32x4 a;
      a[0] = a[1] = a[2] = a[3] = bs[g];
      a = __builtin_amdgcn_mfma_f32_16x16x32_bf16(x0, wih[g][0], a, 0, 0, 0);
      a = __builtin_amdgcn_mfma_f32_16x16x32_bf16(x1, wih[g][1], a, 0, 0, 0);
      accn[g] = a;
    }
  }

  for (int t = 0; t < TT; ++t) {
    // h fragments from LDS buffer (t&1), written last step
    s16x8 hfr[8];
    if (t > 0) {
#pragma unroll
      for (int kf = 0; kf < 8; ++kf) {
        int byte = (lrow * 512 + (kf * 32 + lk8) * 2) ^ ((lrow & 7) << 4);
        hfr[kf] = *(const s16x8*)((const char*)h_lds[t & 1] + byte);
      }
    }

    // prefetch + pack x(t+1)
    s16x8 xn0, xn1;
    if (t < TT - 1) {
      const float* xp = x + ((size_t)(b0 + lrow) * TT + (t + 1)) * II + lk8;
      xn0 = pack_bf8(xp);
      xn1 = pack_bf8(xp + 32);
    }

    // gates for step t: acc = accn (bias + x part) + h @ W_hh^T
    f32x4 acc[4];
#pragma unroll
    for (int g = 0; g < 4; ++g) {
      f32x4 a = accn[g];
      if (t > 0) {
#pragma unroll
        for (int kf = 0; kf < 8; ++kf)
          a = __builtin_amdgcn_mfma_f32_16x16x32_bf16(hfr[kf], whh[g][kf], a,
                                                      0, 0, 0);
      }
      acc[g] = a;
    }

    // x-projection for t+1 (independent of nonlin -> overlaps VALU work)
    if (t < TT - 1) {
#pragma unroll
      for (int g = 0; g < 4; ++g) {
        f32x4 a;
        a[0] = a[1] = a[2] = a[3] = bs[g];
        a = __builtin_amdgcn_mfma_f32_16x16x32_bf16(xn0, wih[g][0], a, 0, 0, 0);
        a = __builtin_amdgcn_mfma_f32_16x16x32_bf16(xn1, wih[g][1], a, 0, 0, 0);
        accn[g] = a;
      }
    }

    // nonlinearity + state update + h writes (to buffer (t+1)&1)
#pragma unroll
    for (int r = 0; r < 4; ++r) {
      float gi = sigm(acc[0][r]);
      float gf = sigm(acc[1][r]);
      float gg = tanh_s(acc[2][r]);
      float go = sigm(acc[3][r]);
      float cn = gf * cst[r] + gi * gg;
      cst[r] = cn;
      float hn = go * tanh_s(cn);
      int row = crow + r;
      int col = col0 + ccol;
      if (t == TT - 1) {
        hf[row][col] = hn;
      } else {
        int byte = (row * 512 + col * 2) ^ ((row & 7) << 4);
        *(ushort*)((char*)h_lds[(t + 1) & 1] + byte) = f2bf(hn);
      }
    }

    __syncthreads();  // writes of h(t+1) visible; reads of buf(t&1) done
  }

  // epilogue: out[b0+wv] = hf[wv][:] . w_out + b_out   (wave wv -> row wv)
  {
    float s = hf[wv][l] * w_out[l] + hf[wv][l + 64] * w_out[l + 64] +
              hf[wv][l + 128] * w_out[l + 128] +
              hf[wv][l + 192] * w_out[l + 192];
#pragma unroll
    for (int off = 32; off >= 1; off >>= 1) s += __shfl_xor(s, off);
    if (l == 0) out[b0 + wv] = s + b_out[0];
  }
}

extern "C" void kernel_launch(void* const* d_in, const int* in_sizes, int n_in,
                              void* d_out, int out_size, void* d_ws, size_t ws_size,
                              hipStream_t stream) {
  const float* x     = (const float*)d_in[0];
  const float* wih   = (const float*)d_in[1];
  const float* whh   = (const float*)d_in[2];
  const float* b_ih  = (const float*)d_in[3];
  const float* b_hh  = (const float*)d_in[4];
  const float* w_out = (const float*)d_in[5];
  const float* b_out = (const float*)d_in[6];
  float* out = (float*)d_out;

  lstm_one<<<64, 1024, 0, stream>>>(x, wih, whh, b_ih, b_hh, w_out, b_out, out);
}

// Round 11
// 8304.868 us; speedup vs baseline: 1.0584x; 1.0584x over previous
//
#include <hip/hip_runtime.h>
#include <hip/hip_bf16.h>

// LSTM: B=1024, T=512, I=64, H=256, O=1
// Round 10 = round-8/9 resubmit (2 prior acquisition timeouts; never ran).
// Structure = round-1 (ran at 7131us) + fix for its measured bottleneck:
//  round-1 loaded W_hh fragments immediately before each MFMA group -> one
//  exposed L2 round trip per (gate,ntile) iteration, 2 waves/SIMD can't hide
//  it. Here: explicit 2-deep register-staged pipeline (stage iter k+2 while
//  MFMAing iter k), bf16 weights pre-converted once into ws, x(t+1)
//  prefetched a step ahead.
// 64 WGs x 512 thr (launch_bounds(512,2) -> 256 VGPR cap, ~190 needed).
// Floor: per-CU L2 read BW: 576KB/step / ~128B/cyc ~ 1.9us/step ~ 1ms total.

typedef float f32x4 __attribute__((ext_vector_type(4)));
typedef short s16x8 __attribute__((ext_vector_type(8)));

#define TT 512
#define II 64
#define HH 256
#define GG 1024  // 4*H

__device__ __forceinline__ ushort f2bf(float f) {
  unsigned u = __builtin_bit_cast(unsigned, f);
  u = (u + 0x7FFFu + ((u >> 16) & 1u)) >> 16;  // RNE
  return (ushort)u;
}

__device__ __forceinline__ float sigm(float x) {
  return 1.0f / (1.0f + __expf(-x));
}
// overflow-safe tanh
__device__ __forceinline__ float tanh_s(float x) {
  float e = __expf(-2.0f * fabsf(x));
  float t = (1.0f - e) / (1.0f + e);
  return copysignf(t, x);
}

__device__ __forceinline__ s16x8 pack_bf8(const float* p) {
  f32x4 a = *(const f32x4*)p;
  f32x4 b = *(const f32x4*)(p + 4);
  s16x8 r;
  r[0] = (short)f2bf(a[0]); r[1] = (short)f2bf(a[1]);
  r[2] = (short)f2bf(a[2]); r[3] = (short)f2bf(a[3]);
  r[4] = (short)f2bf(b[0]); r[5] = (short)f2bf(b[1]);
  r[6] = (short)f2bf(b[2]); r[7] = (short)f2bf(b[3]);
  return r;
}

__global__ void cvt_weights(const float* __restrict__ wih,
                            const float* __restrict__ whh,
                            ushort* __restrict__ ws) {
  int i = blockIdx.x * 256 + threadIdx.x;
  if (i < GG * II) {
    ws[i] = f2bf(wih[i]);
  } else {
    int j = i - GG * II;
    if (j < GG * HH) ws[GG * II + j] = f2bf(whh[j]);
  }
}

template <bool WSBF>
__device__ __forceinline__ s16x8 load_frag(const void* base, int off) {
  if constexpr (WSBF) {
    return *(const s16x8*)((const ushort*)base + off);
  } else {
    return pack_bf8((const float*)base + off);
  }
}

template <bool WSBF>
__global__ __launch_bounds__(512, 2) void lstm_stream(
    const float* __restrict__ x,      // [B,T,I]
    const float* __restrict__ wih_f,  // [4H,I]
    const float* __restrict__ whh_f,  // [4H,H]
    const float* __restrict__ b_ih,   // [4H]
    const float* __restrict__ b_hh,   // [4H]
    const float* __restrict__ w_out,  // [1,H]
    const float* __restrict__ b_out,  // [1]
    const ushort* __restrict__ wsb,   // bf16: [0,64K) W_ih, [64K,..) W_hh
    float* __restrict__ out)          // [B]
{
  __shared__ ushort h_lds[16 * 256];  // bf16 h, XOR-swizzled
  __shared__ float hf[16][256];       // final-step fp32 h

  const int tid  = threadIdx.x;
  const int wv   = tid >> 6;
  const int l    = tid & 63;
  const int lrow = l & 15;          // A row / B col within 16x16 tile
  const int lk8  = (l >> 4) << 3;   // k offset base for A/B frags
  const int crow = (l >> 4) << 2;   // C row base (+reg idx)
  const int ccol = l & 15;          // C col
  const int b0 = blockIdx.x << 4;   // batch base
  const int jw = wv << 5;           // hidden col base for this wave (32 cols)

  // zero h state (t=0 runs the full pipeline against h=0; 1/512 waste)
  {
    s16x8 z = {};
    *(s16x8*)&h_lds[tid * 8] = z;   // 512*8 = 4096 = 16*256
  }

  const void* wih_base = WSBF ? (const void*)wsb : (const void*)wih_f;
  const void* whh_base = WSBF ? (const void*)(wsb + GG * II) : (const void*)whh_f;

  // bias sums (depend on C col only)
  float bs[4][2];
#pragma unroll
  for (int g = 0; g < 4; ++g)
#pragma unroll
    for (int nt = 0; nt < 2; ++nt) {
      int c = g * 256 + jw + nt * 16 + ccol;
      bs[g][nt] = b_ih[c] + b_hh[c];
    }

  float cst[2][4] = {};  // c state: [ntile][reg]

  // x fragments for t=0
  s16x8 xf0, xf1;
  {
    const float* xp = x + (size_t)(b0 + lrow) * TT * II + lk8;
    xf0 = pack_bf8(xp);
    xf1 = pack_bf8(xp + 32);
  }

  __syncthreads();

  // iteration ii -> (g = ii>>1, nt = ii&1); stage slots 0..7 = W_hh kfrags,
  // 8..9 = W_ih kfrags. Double-buffered: stg[ii&1] holds iteration ii.
#define ROWOF(ii) (((ii) >> 1) * 256 + jw + ((ii) & 1) * 16 + lrow)
#define STAGE(ii, buf)                                                        \
  {                                                                           \
    const int row_ = ROWOF(ii);                                               \
    _Pragma("unroll") for (int kf = 0; kf < 8; ++kf)                          \
        stg[buf][kf] = load_frag<WSBF>(whh_base, row_ * HH + kf * 32 + lk8);  \
    _Pragma("unroll") for (int kt = 0; kt < 2; ++kt)                          \
        stg[buf][8 + kt] = load_frag<WSBF>(wih_base, row_ * II + kt * 32 + lk8); \
  }

  for (int t = 0; t < TT; ++t) {
    // h A-fragments from LDS (swizzled)
    s16x8 hfr[8];
#pragma unroll
    for (int kf = 0; kf < 8; ++kf) {
      int byte = (lrow * 512 + (kf * 32 + lk8) * 2) ^ ((lrow & 7) << 4);
      hfr[kf] = *(const s16x8*)((const char*)h_lds + byte);
    }

    // prefetch + pack x(t+1) (issued early; consumed next step)
    s16x8 xn0, xn1;
    if (t < TT - 1) {
      const float* xp = x + ((size_t)(b0 + lrow) * TT + (t + 1)) * II + lk8;
      xn0 = pack_bf8(xp);
      xn1 = pack_bf8(xp + 32);
    }

    f32x4 acc[4][2];
    s16x8 stg[2][10];
    STAGE(0, 0)
    STAGE(1, 1)
#pragma unroll
    for (int ii = 0; ii < 8; ++ii) {
      const int g = ii >> 1, nt = ii & 1, buf = ii & 1;
      f32x4 a;
      a[0] = a[1] = a[2] = a[3] = bs[g][nt];
      a = __builtin_amdgcn_mfma_f32_16x16x32_bf16(xf0, stg[buf][8], a, 0, 0, 0);
      a = __builtin_amdgcn_mfma_f32_16x16x32_bf16(xf1, stg[buf][9], a, 0, 0, 0);
#pragma unroll
      for (int kf = 0; kf < 8; ++kf)
        a = __builtin_amdgcn_mfma_f32_16x16x32_bf16(hfr[kf], stg[buf][kf], a,
                                                    0, 0, 0);
      acc[g][nt] = a;
      // stage iteration ii+2 into the buffer just consumed (WAR: after MFMAs)
      if (ii < 6) STAGE(ii + 2, buf)
    }

    __syncthreads();  // all waves finished reading h_lds

    // nonlinearity + state update; write h_new
#pragma unroll
    for (int nt = 0; nt < 2; ++nt)
#pragma unroll
      for (int r = 0; r < 4; ++r) {
        float gi = sigm(acc[0][nt][r]);
        float gf = sigm(acc[1][nt][r]);
        float gg = tanh_s(acc[2][nt][r]);
        float go = sigm(acc[3][nt][r]);
        float cn = gf * cst[nt][r] + gi * gg;
        cst[nt][r] = cn;
        float hn = go * tanh_s(cn);
        int row = crow + r;
        int col = jw + nt * 16 + ccol;
        int byte = (row * 512 + col * 2) ^ ((row & 7) << 4);
        *(ushort*)((char*)h_lds + byte) = f2bf(hn);
        if (t == TT - 1) hf[row][col] = hn;
      }

    xf0 = xn0;
    xf1 = xn1;
    __syncthreads();
  }

  // epilogue: out[b] = h_last . W_out + b_out   (fp32)
#pragma unroll
  for (int rr = 0; rr < 2; ++rr) {
    int row = wv * 2 + rr;
    float s = 0.f;
#pragma unroll
    for (int m = 0; m < 4; ++m)
      s += hf[row][l + 64 * m] * w_out[l + 64 * m];
#pragma unroll
    for (int off = 32; off >= 1; off >>= 1)
      s += __shfl_xor(s, off);
    if (l == 0) out[b0 + row] = s + b_out[0];
  }
#undef STAGE
#undef ROWOF
}

extern "C" void kernel_launch(void* const* d_in, const int* in_sizes, int n_in,
                              void* d_out, int out_size, void* d_ws, size_t ws_size,
                              hipStream_t stream) {
  const float* x     = (const float*)d_in[0];
  const float* wih   = (const float*)d_in[1];
  const float* whh   = (const float*)d_in[2];
  const float* b_ih  = (const float*)d_in[3];
  const float* b_hh  = (const float*)d_in[4];
  const float* w_out = (const float*)d_in[5];
  const float* b_out = (const float*)d_in[6];
  float* out = (float*)d_out;

  const size_t ws_needed = (size_t)(GG * II + GG * HH) * sizeof(ushort);  // 640 KB
  if (ws_size >= ws_needed) {
    ushort* wsb = (ushort*)d_ws;
    int n = GG * II + GG * HH;
    cvt_weights<<<(n + 255) / 256, 256, 0, stream>>>(wih, whh, wsb);
    lstm_stream<true><<<64, 512, 0, stream>>>(x, wih, whh, b_ih, b_hh, w_out,
                                              b_out, wsb, out);
  } else {
    lstm_stream<false><<<64, 512, 0, stream>>>(x, wih, whh, b_ih, b_hh, w_out,
                                               b_out, nullptr, out);
  }
}